// Round 2
// baseline (144.993 us; speedup 1.0000x reference)
//
#include <hip/hip_runtime.h>

// LieSE3: per row [x, y, p_yaw] -> 4x4 SE(3) matrix with z-only rotation.
//
// Closed form (w = 0.1*p, ts = w^2, th = |w|):
//   A  = sin(th)/(th+eps);  Bc = (1-cos th)/(ts+eps);  C = (1-A)/(ts+eps)
//   R00 = R11 = 1 - Bc*ts;  R10 = A*w = -R01;  R22 = 1
//   V00 = V11 = 1 - C*ts;   V10 = Bc*w = -V01
//   t0 = V00*x - Bw*y;  t1 = Bw*x + V00*y;  rows 2,3 = [0,0,1,0],[0,0,0,1]
//
// R4 = R3 with the nontemporal builtins fed a clang ext_vector_type(4)
// float ("f4") instead of HIP's struct float4 (which the builtin rejects).
// R3 changes recap (vs R2's 1-thread-per-matrix + LDS-staged stores):
//  - XOR-swizzled output staging: logical float4 index j -> j ^ ((j>>5)&7).
//    R2's write smem[4*tid+k] was a 64B-stride ds_write_b128 hitting only
//    banks {0-3,16-19} (~16-way conflict). Swizzled writes spread each
//    4-bank group across exactly 8 lanes (minimum possible); the read side
//    (j = tid+256k) is a within-8 permutation of a contiguous range ->
//    still conflict-free. Same involution both sides.
//  - Input staged via 192 coalesced float4 loads into 3KB LDS (was 3x
//    stride-12 scalar global loads). LDS re-read at stride 3 floats hits
//    all 32 banks (gcd(3,32)=1) -> conflict-free.
//  - Wave-uniform tail guard; all-int indexing (4*B = 8e6 fits int).
//  - Nontemporal loads/stores: pure streaming traffic, skip L2/L3 fill.
// LDS = 3KB in + 16KB out = 19KB -> still 8 blocks/CU (wave cap), max occ.

#define ROTATION_SCALE 0.1f
#define EPS_F 1e-5f

typedef float f4 __attribute__((ext_vector_type(4)));

#define SWZ(j) ((j) ^ (((j) >> 5) & 7))

__global__ __launch_bounds__(256) void lie_se3_kernel(
    const f4* __restrict__ uv4, const float* __restrict__ uvf,
    f4* __restrict__ out, int B, int nf4) {
  __shared__ f4 s_in4[192];   // 256 rows x 3 floats = 768 floats
  __shared__ f4 s_out[1024];  // 256 matrices x 4 rows

  const int tid = threadIdx.x;
  const int blk = blockIdx.x;

  // ---- stage input: 192 contiguous float4 per block ----
  if (tid < 192) {
    int gi = blk * 192 + tid;  // max 1.5e6, fits int
    f4 v = (f4)(0.f);
    if (gi < nf4) v = __builtin_nontemporal_load(&uv4[gi]);
    s_in4[tid] = v;
  }
  __syncthreads();

  const float* s_inf = reinterpret_cast<const float*>(s_in4);
  const int m = blk * 256 + tid;
  const int gf = 3 * m;  // max 6e6, fits int
  float x, y, p;
  if (gf + 3 <= 4 * nf4) {  // all 3 floats covered by the float4 stage
    x = s_inf[3 * tid + 0];
    y = s_inf[3 * tid + 1];
    p = s_inf[3 * tid + 2];
  } else if (m < B) {  // tail floats when 3B % 4 != 0 (not hit for B=2e6)
    x = uvf[gf + 0];
    y = uvf[gf + 1];
    p = uvf[gf + 2];
  } else {
    x = y = p = 0.f;
  }

  float w = p * ROTATION_SCALE;
  float ts = w * w;
  float th = fabsf(w);
  float s = __sinf(th);
  float c = __cosf(th);
  float A = s / (th + EPS_F);
  float Bc = (1.0f - c) / (ts + EPS_F);
  float C = (1.0f - A) / (ts + EPS_F);

  float R00 = 1.0f - Bc * ts;  // == R11
  float Aw = A * w;            // R10 = Aw, R01 = -Aw
  float V00 = 1.0f - C * ts;   // == V11
  float Bw = Bc * w;           // V10 = Bw, V01 = -Bw
  float t0 = V00 * x - Bw * y;
  float t1 = Bw * x + V00 * y;

  // ---- stage output, swizzled (bank-conflict-free both phases) ----
  const int j0 = 4 * tid;
  {
    f4 r0 = {R00, -Aw, 0.f, t0};
    f4 r1 = {Aw, R00, 0.f, t1};
    f4 r2 = {0.f, 0.f, 1.f, 0.f};
    f4 r3 = {0.f, 0.f, 0.f, 1.f};
    s_out[SWZ(j0 + 0)] = r0;
    s_out[SWZ(j0 + 1)] = r1;
    s_out[SWZ(j0 + 2)] = r2;
    s_out[SWZ(j0 + 3)] = r3;
  }
  __syncthreads();

  // ---- contiguous streaming store: 1KB per wave-instruction ----
  const int base = blk * 1024;  // float4 index; max 8e6, fits int
  const int limit = 4 * B;
  if (base + 1024 <= limit) {  // wave-uniform fast path
#pragma unroll
    for (int k = 0; k < 4; ++k) {
      int idx = tid + k * 256;
      __builtin_nontemporal_store(s_out[SWZ(idx)], &out[base + idx]);
    }
  } else {
#pragma unroll
    for (int k = 0; k < 4; ++k) {
      int idx = tid + k * 256;
      if (base + idx < limit)
        __builtin_nontemporal_store(s_out[SWZ(idx)], &out[base + idx]);
    }
  }
}

extern "C" void kernel_launch(void* const* d_in, const int* in_sizes, int n_in,
                              void* d_out, int out_size, void* d_ws, size_t ws_size,
                              hipStream_t stream) {
  const float* uvf = (const float*)d_in[0];
  const f4* uv4 = (const f4*)d_in[0];
  f4* out = (f4*)d_out;
  int B = in_sizes[0] / 3;    // 2,000,000
  int nf4 = in_sizes[0] / 4;  // whole float4s in the input (exact for B=2e6)
  int grid = (B + 255) / 256;
  lie_se3_kernel<<<grid, 256, 0, stream>>>(uv4, uvf, out, B, nf4);
}